// Round 2
// baseline (509.275 us; speedup 1.0000x reference)
//
#include <hip/hip_runtime.h>
#include <cstdint>

#define NCLS 3
#define NPTS 100000
#define NB 2
#define PRE 512
#define POST 100
#define SCORE_TH 0.1f
#define NMS_TH 0.25
#define CAP 1024            // candidate buffer per problem (expect ~690)
#define NBINS 384           // fast-key bins: (key>>17) - (0xBD000000>>17)
#define BIN_SH 17
#define BIN_OFFW (0xBD000000u >> BIN_SH)
#define FMARG 2e-5f         // 2x bound on |f32 sigmoid - f64 sigmoid| (<=1e-6)
#define NPROB (NB * NCLS)
#define NCHUNK 98           // ceil(NPTS/1024) chunks per plane
#define CPB 4               // chunks per hist block
#define NKB 25              // hist blocks per batch (ceil(98/4))
#define WAVES_PER_PROB 2304 // 36 upper-tri 64x64 cells x 64 rows
#define BLOCKS_PER_PROB 576 // WAVES_PER_PROB / 4

// ---------------- ws layout (bytes) ----------------
// hist_part : u32 [2*25*3*384]      @ 0         (230,400; plain stores, fully
//                                                written by hist_kernel)
// ctrs      : u32 [18]              @ 230,400   (doneB[6], doneC[6],
//                                                cand_cnt[6]; zeroed by
//                                                hist block 0 -> visible to
//                                                K2/K3 via kernel boundary)
// cand      : u64 [6*CAP]           @ 230,528   (49,152)
// mask      : u64 [6*PRE*8]         @ 279,680   (196,608; upper-tri always
//                                                stored; lower-tri garbage
//                                                provably harmless)
// cand_idx  : u32 [6*PRE]           @ 476,288   (12,288)
// cand_scr  : f32 [6*PRE]           @ 488,576   (12,288)
// boxdata   : f64 [6*PRE*20]        @ 500,864   (491,520)
// screen    : f32 [6*PRE*8]         @ 992,384   (98,304)
// total ~1.04 MB, no memsets anywhere

__device__ __forceinline__ uint32_t score_key(float x)
{
    // EXACT path: f64 sigmoid rounded to f32 == reference (absmax 0.0)
    double sd = 1.0 / (1.0 + exp(-(double)x));
    float s = (float)sd;
    if (!(s >= SCORE_TH)) s = -1.0f;
    uint32_t u = __float_as_uint(s);
    return (u & 0x80000000u) ? ~u : (u | 0x80000000u);
}

__device__ __forceinline__ float fast_sig(float x)
{
    return 1.0f / (1.0f + __expf(-x));
}

// monotone bin of a (possibly margin-adjusted) f32 score
__device__ __forceinline__ int fast_bin(float s)
{
    float v = (s >= SCORE_TH) ? s : -1.0f;
    uint32_t u = __float_as_uint(v);
    uint32_t kk = (u & 0x80000000u) ? ~u : (u | 0x80000000u);
    int b = (int)(kk >> BIN_SH) - (int)BIN_OFFW;
    return b < 0 ? 0 : (b > NBINS - 1 ? NBINS - 1 : b);
}

// 50 blocks (2 batches x 25), 4 chunks each: LDS histogram -> per-block
// partial stores (no zero-init needed anywhere). Block 0 also zeroes the
// 18 control words consumed by the later kernels (ordered by boundary).
__global__ __launch_bounds__(1024) void hist_kernel(
    const float* __restrict__ cls, uint32_t* __restrict__ hist_part,
    uint32_t* __restrict__ ctrs)
{
    __shared__ uint32_t lh[NCLS][2][NBINS];   // 2 copies halve hot-bin chains
    const int tid = threadIdx.x;
    for (int t = tid; t < NCLS * 2 * NBINS; t += 1024) ((uint32_t*)lh)[t] = 0;
    if (blockIdx.x == 0 && tid < 18) ctrs[tid] = 0;
    __syncthreads();

    const int b = blockIdx.x / NKB, kb = blockIdx.x % NKB;
    const int par = (tid >> 6) & 1;
    const float* base = cls + (size_t)b * NPTS * NCLS;
    #pragma unroll
    for (int c = 0; c < CPB; ++c) {
        int i = (kb * CPB + c) * 1024 + tid;
        if (i < NPTS) {
            const float* cp = base + (size_t)i * NCLS;
            #pragma unroll
            for (int k = 0; k < NCLS; ++k)
                atomicAdd(&lh[k][par][fast_bin(fast_sig(cp[k]))], 1u);
        }
    }
    __syncthreads();
    uint32_t* P = hist_part + (size_t)((b * NKB + kb) * NCLS) * NBINS;
    for (int t = tid; t < NCLS * NBINS; t += 1024)
        P[t] = lh[t / NBINS][0][t % NBINS] + lh[t / NBINS][1][t % NBINS];
}

// 588 blocks (6 problems x 98 chunks). Each block: redundant pivot reduce
// (cheap, avoids a dedicated dispatch), compact its chunk, then the LAST
// block per problem (threadfence + done-counter) sorts + builds geometry.
__global__ __launch_bounds__(1024) void compact_sort_kernel(
    const float* __restrict__ cls, const float* __restrict__ boxes,
    const uint32_t* __restrict__ hist_part, uint32_t* __restrict__ ctrs,
    unsigned long long* __restrict__ cand,
    uint32_t* __restrict__ cand_idx, float* __restrict__ cand_score,
    double* __restrict__ boxdata, float* __restrict__ screen)
{
    const int p = blockIdx.x / NCHUNK, cb = blockIdx.x % NCHUNK;
    const int b = p / NCLS, k = p % NCLS;
    const int tid = threadIdx.x;

    __shared__ unsigned long long skey[CAP];  // stage, then sort buffer
    __shared__ uint32_t sbins[NBINS];
    __shared__ uint32_t lcnt, lbase, pivot_s, lastf;

    if (tid < NBINS) sbins[tid] = 0;
    if (tid == 0) { lcnt = 0; pivot_s = 0; }
    __syncthreads();

    // ---- redundant per-block pivot: reduce 25 partials for problem p ----
    for (int idx = tid; idx < NKB * NBINS; idx += 1024) {
        int kb = idx / NBINS, bin = idx % NBINS;
        uint32_t v = hist_part[(size_t)((b * NKB + kb) * NCLS + k) * NBINS + bin];
        if (v) atomicAdd(&sbins[bin], v);
    }
    __syncthreads();
    for (int off = 1; off < NBINS; off <<= 1) {     // suffix scan
        uint32_t v = 0;
        if (tid < NBINS && tid + off < NBINS) v = sbins[tid + off];
        __syncthreads();
        if (tid < NBINS) sbins[tid] += v;
        __syncthreads();
    }
    if (tid < NBINS && sbins[tid] >= PRE &&
        (tid == NBINS - 1 || sbins[tid + 1] < PRE))
        pivot_s = (uint32_t)tid;                    // unique writer
    __syncthreads();
    const uint32_t pb = pivot_s;

    // ---- compact this chunk (<=1 survivor/thread -> LDS stage safe) ----
    const int i = cb * 1024 + tid;
    bool sv = false;
    unsigned long long entry = 0;
    if (i < NPTS) {
        float x = cls[((size_t)b * NPTS + i) * NCLS + k];
        float sfv = fast_sig(x);
        if ((uint32_t)fast_bin(sfv + FMARG) >= pb) {
            uint32_t kk = score_key(x);
            entry = ((unsigned long long)kk << 32) | (uint32_t)(~(uint32_t)i);
            sv = true;
        }
    }
    if (sv) { uint32_t s = atomicAdd(&lcnt, 1u); skey[s] = entry; }
    __syncthreads();
    if (tid == 0 && lcnt) lbase = atomicAdd(&ctrs[12 + p], lcnt);
    __syncthreads();
    {
        const uint32_t n = lcnt;
        if (n) {
            const uint32_t bs = lbase;
            for (uint32_t e = tid; e < n; e += 1024) {
                uint32_t g = bs + e;
                if (g < CAP) cand[(size_t)p * CAP + g] = skey[e];
            }
        }
    }

    // ---- last-block gate (release: fence all threads, barrier, inc) ----
    __threadfence();
    __syncthreads();
    if (tid == 0)
        lastf = (atomicAdd(&ctrs[p], 1u) == NCHUNK - 1);
    __syncthreads();
    if (!lastf) return;
    __threadfence();                                // acquire

    const int cnt0 = (int)atomicAdd(&ctrs[12 + p], 0u);
    const int cnt = cnt0 < CAP ? cnt0 : CAP;
    unsigned long long val = (tid < cnt) ? cand[(size_t)p * CAP + tid] : 0ull;
    __syncthreads();

    // ---- bitonic sort, descending; j>=64 via LDS, j<=32 via shfl ----
    for (int k2 = 2; k2 <= CAP; k2 <<= 1) {
        const bool up = (tid & k2) == 0;
        for (int j = k2 >> 1; j >= 64; j >>= 1) {
            skey[tid] = val;
            __syncthreads();
            unsigned long long o = skey[tid ^ j];
            __syncthreads();
            const bool keepLarge = (((tid & j) == 0) == up);
            val = keepLarge ? (val >= o ? val : o) : (val <= o ? val : o);
        }
        int js = (k2 >> 1) < 32 ? (k2 >> 1) : 32;
        for (int j = js; j >= 1; j >>= 1) {
            unsigned long long o = __shfl_xor(val, j);
            const bool keepLarge = (((tid & j) == 0) == up);
            val = keepLarge ? (val >= o ? val : o) : (val <= o ? val : o);
        }
    }

    // ---- top-512 decode + f64 geometry + f32 screen ----
    if (tid >= PRE) return;
    unsigned long long key = val;
    double* D = boxdata + (size_t)(p * PRE + tid) * 20;
    float* S = screen + (size_t)(p * PRE + tid) * 8;
    if (key == 0ull) {
        cand_idx[p * PRE + tid] = 0;
        cand_score[p * PRE + tid] = -1.0f;
        #pragma unroll
        for (int m = 0; m < 20; ++m) D[m] = 0.0;
        #pragma unroll
        for (int m = 0; m < 8; ++m) S[m] = 0.0f;
        return;
    }
    uint32_t idx = ~((uint32_t)key);
    uint32_t ov = (uint32_t)(key >> 32);
    uint32_t ub = (ov & 0x80000000u) ? (ov ^ 0x80000000u) : ~ov;
    float sc = __uint_as_float(ub);
    cand_idx[p * PRE + tid] = idx;
    cand_score[p * PRE + tid] = sc;

    const float* bp = boxes + ((size_t)b * NPTS + idx) * 7;
    double x = bp[0], y = bp[1], z = bp[2];
    double dx = bp[3], dy = bp[4], dz = bp[5], r = bp[6];
    double c = cos(r), s = sin(r);
    double hx = 0.5 * dx, hy = 0.5 * dy;
    double zlo = z - 0.5 * dz, zhi = z + 0.5 * dz;
    double rad = sqrt(hx * hx + hy * hy);
    D[0] = x; D[1] = y; D[2] = c; D[3] = s; D[4] = hx; D[5] = hy;
    D[6] = zlo; D[7] = zhi; D[8] = dx * dy * dz; D[9] = rad;
    const double lxs[4] = { hx, -hx, -hx,  hx };
    const double lys[4] = { hy,  hy, -hy, -hy };
    #pragma unroll
    for (int m = 0; m < 4; ++m) {
        D[10 + m] = x + lxs[m] * c - lys[m] * s;
        D[14 + m] = y + lxs[m] * s + lys[m] * c;
    }
    S[0] = (float)x; S[1] = (float)y; S[2] = (float)zlo; S[3] = (float)zhi;
    S[4] = (float)rad; S[5] = 0.0f; S[6] = 0.0f; S[7] = 0.0f;
}

// 3456 blocks x 256 (4 waves, block-uniform problem). IoU with exact
// early-outs (hz, SAT separation, IoU upper bound) before the polygon
// build. Last block per problem runs the keep-iterating NMS + output.
__global__ __launch_bounds__(256) void iou_nms_kernel(
    const float* __restrict__ screen, const double* __restrict__ boxdata,
    const float* __restrict__ boxes, const uint32_t* __restrict__ cand_idx,
    const float* __restrict__ cand_score, uint32_t* __restrict__ ctrs,
    unsigned long long* __restrict__ mask, float* __restrict__ out)
{
    __shared__ unsigned long long smask[PRE * 8];   // 32 KB (nms stage)
    __shared__ float sscore[PRE];
    __shared__ int slist[POST];
    __shared__ int scnt;
    __shared__ uint32_t lastf;

    const int W = blockIdx.x * 4 + (threadIdx.x >> 6);
    const int lane = threadIdx.x & 63;
    const int prob = W / WAVES_PER_PROB;
    int t = W - prob * WAVES_PER_PROB;
    int cell = t >> 6, r = t & 63;
    int wi = 0;
    while (cell >= 8 - wi) { cell -= 8 - wi; ++wi; }
    const int wj = wi + cell;
    const int bi = wi * 64 + r;
    const int j = wj * 64 + lane;

    bool surv = false;
    {
        const float* SA = screen + (size_t)(prob * PRE + bi) * 8;
        const float* SB = screen + (size_t)(prob * PRE + j) * 8;
        if (j > bi) {
            float4 a4 = *(const float4*)SA;           // x,y,zlo,zhi
            float4 b4 = *(const float4*)SB;
            float hz = fminf(a4.w, b4.w) - fmaxf(a4.z, b4.z);
            if (hz > 0.0f) {
                float ddx = a4.x - b4.x, ddy = a4.y - b4.y;
                float rs = SA[4] + SB[4] + 0.01f;
                surv = (ddx * ddx + ddy * ddy <= rs * rs);
            }
        }
    }
    unsigned long long sm = __ballot(surv);   // wave-uniform survivor set
    unsigned long long supw = 0ull;
    const double* A = boxdata + (size_t)(prob * PRE + bi) * 20;

    while (sm) {
        int jb = __ffsll(sm) - 1;
        sm &= sm - 1ull;
        const int bj = wj * 64 + jb;
        const double* B = boxdata + (size_t)(prob * PRE + bj) * 20;

        // ---- exact, wave-uniform early-outs (skip the polygon body) ----
        double hzd = fmin(A[7], B[7]) - fmax(A[6], B[6]);
        if (hzd <= 0.0) continue;                    // no z overlap -> !sup
        {
            double ddx = B[0] - A[0], ddy = B[1] - A[1];
            double ca = A[2], sa = A[3], cb2 = B[2], sb2 = B[3];
            double cd = fabs(ca * cb2 + sa * sb2);   // |cos dtheta|
            double sd = fabs(sa * cb2 - ca * sb2);   // |sin dtheta|
            double pax = fabs(ddx * ca + ddy * sa);
            double pay = fabs(-ddx * sa + ddy * ca);
            double pbx = fabs(ddx * cb2 + ddy * sb2);
            double pby = fabs(-ddx * sb2 + ddy * cb2);
            // SAT: strictly separated => inter == 0 => !sup (exact)
            if (pax > A[4] + B[4] * cd + B[5] * sd) continue;
            if (pay > A[5] + B[4] * sd + B[5] * cd) continue;
            if (pbx > B[4] + A[4] * cd + A[5] * sd) continue;
            if (pby > B[5] + A[4] * sd + A[5] * cd) continue;
            // IoU upper bound: inter <= min(areaA, areaB); f increasing in i3
            double areaA = 4.0 * A[4] * A[5], areaB = 4.0 * B[4] * B[5];
            double i3m = fmin(areaA, areaB) * hzd;
            double den = A[8] + B[8] - i3m;
            if (den < 1e-8) den = 1e-8;
            if (!(i3m / den > (double)NMS_TH)) continue;
        }

        // lane owns one candidate point: 0-3 A-corners, 4-7 B-corners,
        // 8-23 edge intersections (reference construction order)
        double PX = 0.0, PY = 0.0;
        bool valid = false;
        if (lane < 8) {
            const double* S = (lane < 4) ? A : B;
            const double* O = (lane < 4) ? B : A;
            int m = lane & 3;
            PX = S[10 + m]; PY = S[14 + m];
            double rx = PX - O[0], ry = PY - O[1];
            double u =  rx * O[2] + ry * O[3];
            double v = -rx * O[3] + ry * O[2];
            valid = (fabs(u) <= O[4] + 1e-5) && (fabs(v) <= O[5] + 1e-5);
        } else if (lane < 24) {
            int e = lane - 8, m = e >> 2, nn = e & 3;
            double ax = A[10 + m], ay = A[14 + m];
            double rax = A[10 + ((m + 1) & 3)] - ax;
            double ray = A[14 + ((m + 1) & 3)] - ay;
            double bx = B[10 + nn], by = B[14 + nn];
            double rbx = B[10 + ((nn + 1) & 3)] - bx;
            double rby = B[14 + ((nn + 1) & 3)] - by;
            double d = rax * rby - ray * rbx;
            if (fabs(d) > 1e-8) {
                double qx = bx - ax, qy = by - ay;
                double tt = (qx * rby - qy * rbx) / d;
                double uu = (qx * ray - qy * rax) / d;
                valid = (tt >= 0.0 && tt <= 1.0 && uu >= 0.0 && uu <= 1.0);
                PX = ax + tt * rax; PY = ay + tt * ray;
            }
        }
        if (!valid) { PX = 0.0; PY = 0.0; }

        unsigned long long bal = __ballot(valid);
        int cnt = __popcll(bal);
        double sx = PX, sy = PY;
        #pragma unroll
        for (int off = 16; off; off >>= 1) {
            sx += __shfl_xor(sx, off);
            sy += __shfl_xor(sy, off);
        }
        int cdiv = cnt > 0 ? cnt : 1;
        double cxc = sx / cdiv, cyc = sy / cdiv;

        double ang = valid ? atan2(PY - cyc, PX - cxc) : 1e9;
        int sidx = lane;

        #pragma unroll
        for (int k = 2; k <= 32; k <<= 1) {
            #pragma unroll
            for (int jj = k >> 1; jj > 0; jj >>= 1) {
                double oang = __shfl_xor(ang, jj);
                double opx  = __shfl_xor(PX, jj);
                double opy  = __shfl_xor(PY, jj);
                int    oidx = __shfl_xor(sidx, jj);
                bool iLow = (lane & jj) == 0;
                bool dirUp = (lane & k) == 0;
                bool mineFirst = (ang < oang) || (ang == oang && sidx < oidx);
                bool keepMine = (mineFirst == (iLow == dirUp));
                if (!keepMine) { ang = oang; PX = opx; PY = opy; sidx = oidx; }
            }
        }

        double nxp = __shfl(PX, (lane + 1) & 31);
        double nyp = __shfl(PY, (lane + 1) & 31);
        double fx  = __shfl(PX, 0);
        double fy  = __shfl(PY, 0);
        bool last = (lane == cnt - 1);
        double qx = last ? fx : nxp, qy = last ? fy : nyp;
        double contrib = 0.0;
        if (lane < cnt)
            contrib = (PX - cxc) * (qy - cyc) - (PY - cyc) * (qx - cxc);
        #pragma unroll
        for (int off = 16; off; off >>= 1) contrib += __shfl_xor(contrib, off);
        double inter = (cnt >= 3) ? 0.5 * fabs(contrib) : 0.0;

        if (lane == 0) {
            double zt = fmin(A[7], B[7]);
            double zb = fmax(A[6], B[6]);
            double hz = zt - zb;
            bool sup = false;
            if (hz > 0.0) {
                double i3 = inter * hz;
                double den = A[8] + B[8] - i3;
                if (den < 1e-8) den = 1e-8;
                sup = (i3 / den) > (double)NMS_TH;
            }
            if (sup) supw |= 1ull << jb;
        }
    }

    if (lane == 0)
        mask[(size_t)(prob * PRE + bi) * 8 + wj] = supw;   // exclusive word

    // ---- last-block gate -> NMS + output for this problem ----
    __threadfence();
    __syncthreads();
    if (threadIdx.x == 0)
        lastf = (atomicAdd(&ctrs[6 + prob], 1u) == BLOCKS_PER_PROB - 1);
    __syncthreads();
    if (!lastf) return;
    __threadfence();                                // acquire

    const int p = prob, b = p / NCLS, k = p % NCLS;
    const int tid = threadIdx.x;
    for (int w = tid; w < PRE * 8; w += 256)
        smask[w] = mask[(size_t)p * PRE * 8 + w];
    for (int i2 = tid; i2 < PRE; i2 += 256)
        sscore[i2] = cand_score[p * PRE + i2];
    __syncthreads();

    // Keep-iterating greedy scan: <=100 iterations (one per kept box)
    // instead of one per row. rem = not-yet-processed valid set; picking
    // the lowest set bit i guarantees all bits < i are clear, so garbage
    // lower-triangle mask bits (columns < i) remain provably harmless.
    if (tid < 64) {
        const int ln = tid;
        unsigned long long rem = 0ull;
        #pragma unroll
        for (int w = 0; w < 8; ++w) {
            unsigned long long bw = __ballot(sscore[w * 64 + ln] >= SCORE_TH);
            if (ln == w) rem = bw;
        }
        int c = 0;
        for (;;) {
            int cv = rem ? ((ln << 6) + (__ffsll(rem) - 1)) : 4096;
            int o1 = __shfl_xor(cv, 1); cv = cv < o1 ? cv : o1;
            int o2 = __shfl_xor(cv, 2); cv = cv < o2 ? cv : o2;
            int o4 = __shfl_xor(cv, 4); cv = cv < o4 ? cv : o4;
            int i = __shfl(cv, 0);
            if (i >= 4096) break;
            if (ln == 0) slist[c] = i;
            ++c;
            if (c >= POST) break;
            unsigned long long mm = (ln < 8) ? smask[i * 8 + ln] : 0ull;
            if (ln == (i >> 6)) mm |= 1ull << (i & 63);
            rem &= ~mm;
        }
        if (ln == 0) scnt = c;
    }
    __syncthreads();

    const int cnt2 = scnt;
    for (int t2 = tid; t2 < POST; t2 += 256) {
        int row = b * (NCLS * POST) + k * POST + t2;          // 0..599
        float* ob = out + (size_t)row * 7;
        float* os = out + (size_t)NB * NCLS * POST * 7 + row;
        float* ol = out + (size_t)NB * NCLS * POST * 7 + (size_t)NB * NCLS * POST + row;
        if (t2 < cnt2) {
            int rr = slist[t2];
            uint32_t idx = cand_idx[p * PRE + rr];
            const float* bp = boxes + ((size_t)b * NPTS + idx) * 7;
            #pragma unroll
            for (int c7 = 0; c7 < 7; ++c7) ob[c7] = bp[c7];
            *os = sscore[rr];
            *ol = (float)(k + 1);
        } else {
            #pragma unroll
            for (int c7 = 0; c7 < 7; ++c7) ob[c7] = 0.0f;
            *os = 0.0f;
            *ol = 0.0f;
        }
    }
}

extern "C" void kernel_launch(void* const* d_in, const int* in_sizes, int n_in,
                              void* d_out, int out_size, void* d_ws, size_t ws_size,
                              hipStream_t stream)
{
    (void)in_sizes; (void)n_in; (void)out_size; (void)ws_size;
    const float* cls   = (const float*)d_in[0];   // (2,100000,3) f32
    const float* boxes = (const float*)d_in[1];   // (2,100000,7) f32
    float* out = (float*)d_out;

    char* ws = (char*)d_ws;
    uint32_t* hist_part   = (uint32_t*)(ws);
    uint32_t* ctrs        = (uint32_t*)(ws + 230400);
    unsigned long long* cand = (unsigned long long*)(ws + 230528);
    unsigned long long* mask = (unsigned long long*)(ws + 279680);
    uint32_t* cand_idx    = (uint32_t*)(ws + 476288);
    float*    cand_score  = (float*)   (ws + 488576);
    double*   boxdata     = (double*)  (ws + 500864);
    float*    screen      = (float*)   (ws + 992384);

    // 3 dispatches (was 6): each kernel-boundary gap measured ~13 us.
    hipLaunchKernelGGL(hist_kernel, dim3(NB * NKB), dim3(1024), 0, stream,
                       cls, hist_part, ctrs);
    hipLaunchKernelGGL(compact_sort_kernel, dim3(NPROB * NCHUNK), dim3(1024),
                       0, stream, cls, boxes, hist_part, ctrs, cand,
                       cand_idx, cand_score, boxdata, screen);
    hipLaunchKernelGGL(iou_nms_kernel, dim3(NPROB * BLOCKS_PER_PROB),
                       dim3(256), 0, stream, screen, boxdata, boxes,
                       cand_idx, cand_score, ctrs, mask, out);
}

// Round 4
// 142.632 us; speedup vs baseline: 3.5706x; 3.5706x over previous
//
#include <hip/hip_runtime.h>
#include <cstdint>

#define NCLS 3
#define NPTS 100000
#define NB 2
#define PRE 512
#define POST 100
#define SCORE_TH 0.1f
#define NMS_TH 0.25
#define CAP 1024            // candidate buffer per problem (expect ~690)
#define NBINS 384           // fast-key bins: (key>>17) - (0xBD000000>>17)
#define BIN_SH 17
#define BIN_OFFW (0xBD000000u >> BIN_SH)
#define FMARG 2e-5f         // 2x bound on |f32 sigmoid - f64 sigmoid| (<=1e-6)
#define NPROB (NB * NCLS)
#define NCHUNK 98           // ceil(NPTS/1024) chunks per plane
#define CPB 4               // chunks per hist block
#define NKB 25              // hist blocks per batch (ceil(98/4))
#define WAVES_PER_PROB 2304 // 36 upper-tri 64x64 cells x 64 rows

// ---------------- ws layout (bytes) ----------------
// hist_part : u32 [2*25*3*384]  @ 0         (230,400; plain stores, fully
//                                            written by hist_kernel)
// ctrs      : u32 [8]           @ 230,528   (cand_cnt[6]; zeroed by hist
//                                            block 0 -> ordered by boundary)
// cand      : u64 [6*CAP]       @ 230,528+? see offsets below
// Layout (R2-verified offsets):
//   hist_part @ 0, ctrs @ 230,400(+128 pad -> 230,528 region start for cand)
//   cand      @ 230,528  (49,152)
//   mask      @ 279,680  (196,608; upper-tri always stored by iou_kernel;
//                         lower-tri garbage provably harmless)
//   cand_idx  @ 476,288  (12,288)
//   cand_scr  @ 488,576  (12,288)
//   boxdata   @ 500,864  (491,520)
//   screen    @ 992,384  (98,304)
// total ~1.09 MB. No memsets, no fences, no gates: kernel boundaries are
// the ONLY cross-block ordering primitive (R2: per-block fences = 7x slow;
// R3: grid.sync plain-store visibility = wrong results).

__device__ __forceinline__ uint32_t score_key(float x)
{
    // EXACT path: f64 sigmoid rounded to f32 == reference (absmax 0.0)
    double sd = 1.0 / (1.0 + exp(-(double)x));
    float s = (float)sd;
    if (!(s >= SCORE_TH)) s = -1.0f;
    uint32_t u = __float_as_uint(s);
    return (u & 0x80000000u) ? ~u : (u | 0x80000000u);
}

__device__ __forceinline__ float fast_sig(float x)
{
    return 1.0f / (1.0f + __expf(-x));
}

// monotone bin of a (possibly margin-adjusted) f32 score
__device__ __forceinline__ int fast_bin(float s)
{
    float v = (s >= SCORE_TH) ? s : -1.0f;
    uint32_t u = __float_as_uint(v);
    uint32_t kk = (u & 0x80000000u) ? ~u : (u | 0x80000000u);
    int b = (int)(kk >> BIN_SH) - (int)BIN_OFFW;
    return b < 0 ? 0 : (b > NBINS - 1 ? NBINS - 1 : b);
}

// 50 blocks (2 batches x 25), 4 chunks each: LDS histogram -> per-block
// partial stores (no zero-init needed anywhere). Block 0 also zeroes the
// candidate counters consumed by compact (ordered by kernel boundary).
__global__ __launch_bounds__(1024) void hist_kernel(
    const float* __restrict__ cls, uint32_t* __restrict__ hist_part,
    uint32_t* __restrict__ ctrs)
{
    __shared__ uint32_t lh[NCLS][2][NBINS];   // 2 copies halve hot-bin chains
    const int tid = threadIdx.x;
    for (int t = tid; t < NCLS * 2 * NBINS; t += 1024) ((uint32_t*)lh)[t] = 0;
    if (blockIdx.x == 0 && tid < 8) ctrs[tid] = 0;
    __syncthreads();

    const int b = blockIdx.x / NKB, kb = blockIdx.x % NKB;
    const int par = (tid >> 6) & 1;
    const float* base = cls + (size_t)b * NPTS * NCLS;
    #pragma unroll
    for (int c = 0; c < CPB; ++c) {
        int i = (kb * CPB + c) * 1024 + tid;
        if (i < NPTS) {
            const float* cp = base + (size_t)i * NCLS;
            #pragma unroll
            for (int k = 0; k < NCLS; ++k)
                atomicAdd(&lh[k][par][fast_bin(fast_sig(cp[k]))], 1u);
        }
    }
    __syncthreads();
    uint32_t* P = hist_part + (size_t)((b * NKB + kb) * NCLS) * NBINS;
    for (int t = tid; t < NCLS * NBINS; t += 1024)
        P[t] = lh[t / NBINS][0][t % NBINS] + lh[t / NBINS][1][t % NBINS];
}

// 588 blocks (6 problems x 98 chunks). Redundant per-block pivot reduce
// (cheap; avoids a dedicated pivot dispatch + its ~13us boundary), then
// compact this block's chunk into global cand via LDS stage + ONE global
// atomicAdd per block. No gates, no fences.
__global__ __launch_bounds__(1024) void compact_kernel(
    const float* __restrict__ cls, const uint32_t* __restrict__ hist_part,
    uint32_t* __restrict__ ctrs, unsigned long long* __restrict__ cand)
{
    const int p = blockIdx.x / NCHUNK, cb = blockIdx.x % NCHUNK;
    const int b = p / NCLS, k = p % NCLS;
    const int tid = threadIdx.x;

    __shared__ unsigned long long stage[1024];
    __shared__ uint32_t sbins[NBINS];
    __shared__ uint32_t lcnt, lbase, pivot_s;

    if (tid < NBINS) sbins[tid] = 0;
    if (tid == 0) { lcnt = 0; pivot_s = 0; }
    __syncthreads();

    // ---- redundant pivot: reduce 25 partials for problem p ----
    for (int idx = tid; idx < NKB * NBINS; idx += 1024) {
        int kb = idx / NBINS, bin = idx % NBINS;
        uint32_t v = hist_part[(size_t)((b * NKB + kb) * NCLS + k) * NBINS + bin];
        if (v) atomicAdd(&sbins[bin], v);
    }
    __syncthreads();
    for (int off = 1; off < NBINS; off <<= 1) {     // suffix scan
        uint32_t v = 0;
        if (tid < NBINS && tid + off < NBINS) v = sbins[tid + off];
        __syncthreads();
        if (tid < NBINS) sbins[tid] += v;
        __syncthreads();
    }
    if (tid < NBINS && sbins[tid] >= PRE &&
        (tid == NBINS - 1 || sbins[tid + 1] < PRE))
        pivot_s = (uint32_t)tid;                    // unique writer
    __syncthreads();
    const uint32_t pb = pivot_s;

    // ---- compact this chunk (<=1 survivor/thread -> LDS stage safe) ----
    const int i = cb * 1024 + tid;
    bool sv = false;
    unsigned long long entry = 0;
    if (i < NPTS) {
        float x = cls[((size_t)b * NPTS + i) * NCLS + k];
        float sfv = fast_sig(x);
        if ((uint32_t)fast_bin(sfv + FMARG) >= pb) {
            uint32_t kk = score_key(x);
            entry = ((unsigned long long)kk << 32) | (uint32_t)(~(uint32_t)i);
            sv = true;
        }
    }
    if (sv) { uint32_t s = atomicAdd(&lcnt, 1u); stage[s] = entry; }
    __syncthreads();
    if (tid == 0 && lcnt) lbase = atomicAdd(&ctrs[p], lcnt);
    __syncthreads();
    const uint32_t n = lcnt;
    if (n) {
        const uint32_t bs = lbase;
        for (uint32_t e = tid; e < n; e += 1024) {
            uint32_t g = bs + e;
            if (g < CAP) cand[(size_t)p * CAP + g] = stage[e];
        }
    }
}

// 6 blocks x 1024: bitonic sort (descending) + top-512 decode + f64
// geometry + f32 screen. j>=64 exchange via LDS, j<=32 via shfl.
__global__ __launch_bounds__(1024) void sort_geom_kernel(
    const float* __restrict__ boxes, const unsigned long long* __restrict__ cand,
    const uint32_t* __restrict__ ctrs, uint32_t* __restrict__ cand_idx,
    float* __restrict__ cand_score, double* __restrict__ boxdata,
    float* __restrict__ screen)
{
    const int p = blockIdx.x, b = p / NCLS;
    const int tid = threadIdx.x;
    __shared__ unsigned long long skey[CAP];

    const int cnt0 = (int)ctrs[p];
    const int cnt = cnt0 < CAP ? cnt0 : CAP;
    unsigned long long val = (tid < cnt) ? cand[(size_t)p * CAP + tid] : 0ull;
    __syncthreads();

    for (int k2 = 2; k2 <= CAP; k2 <<= 1) {
        const bool up = (tid & k2) == 0;
        for (int j = k2 >> 1; j >= 64; j >>= 1) {
            skey[tid] = val;
            __syncthreads();
            unsigned long long o = skey[tid ^ j];
            __syncthreads();
            const bool keepLarge = (((tid & j) == 0) == up);
            val = keepLarge ? (val >= o ? val : o) : (val <= o ? val : o);
        }
        int js = (k2 >> 1) < 32 ? (k2 >> 1) : 32;
        for (int j = js; j >= 1; j >>= 1) {
            unsigned long long o = __shfl_xor(val, j);
            const bool keepLarge = (((tid & j) == 0) == up);
            val = keepLarge ? (val >= o ? val : o) : (val <= o ? val : o);
        }
    }

    if (tid >= PRE) return;
    unsigned long long key = val;
    double* D = boxdata + (size_t)(p * PRE + tid) * 20;
    float* S = screen + (size_t)(p * PRE + tid) * 8;
    if (key == 0ull) {                       // defensive: can't happen normally
        cand_idx[p * PRE + tid] = 0;
        cand_score[p * PRE + tid] = -1.0f;
        #pragma unroll
        for (int m = 0; m < 20; ++m) D[m] = 0.0;
        #pragma unroll
        for (int m = 0; m < 8; ++m) S[m] = 0.0f;
        return;
    }
    uint32_t idx = ~((uint32_t)key);
    uint32_t ov = (uint32_t)(key >> 32);
    uint32_t ub = (ov & 0x80000000u) ? (ov ^ 0x80000000u) : ~ov;
    float sc = __uint_as_float(ub);
    cand_idx[p * PRE + tid] = idx;
    cand_score[p * PRE + tid] = sc;

    const float* bp = boxes + ((size_t)b * NPTS + idx) * 7;
    double x = bp[0], y = bp[1], z = bp[2];
    double dx = bp[3], dy = bp[4], dz = bp[5], r = bp[6];
    double c = cos(r), s = sin(r);
    double hx = 0.5 * dx, hy = 0.5 * dy;
    double zlo = z - 0.5 * dz, zhi = z + 0.5 * dz;
    double rad = sqrt(hx * hx + hy * hy);
    D[0] = x; D[1] = y; D[2] = c; D[3] = s; D[4] = hx; D[5] = hy;
    D[6] = zlo; D[7] = zhi; D[8] = dx * dy * dz; D[9] = rad;
    const double lxs[4] = { hx, -hx, -hx,  hx };
    const double lys[4] = { hy,  hy, -hy, -hy };
    #pragma unroll
    for (int m = 0; m < 4; ++m) {
        D[10 + m] = x + lxs[m] * c - lys[m] * s;
        D[14 + m] = y + lxs[m] * s + lys[m] * c;
    }
    S[0] = (float)x; S[1] = (float)y; S[2] = (float)zlo; S[3] = (float)zhi;
    S[4] = (float)rad; S[5] = 0.0f; S[6] = 0.0f; S[7] = 0.0f;
}

// 3456 blocks x 256 (4 waves each). Screen + exact early-outs (hz, SAT
// separation, IoU upper bound -- all exact, R2-verified absmax 0.0) before
// the f64 polygon body. No LDS (max occupancy), no gates.
__global__ __launch_bounds__(256) void iou_kernel(
    const float* __restrict__ screen, const double* __restrict__ boxdata,
    unsigned long long* __restrict__ mask)
{
    const int W = blockIdx.x * 4 + (threadIdx.x >> 6);
    const int lane = threadIdx.x & 63;
    const int prob = W / WAVES_PER_PROB;
    int t = W - prob * WAVES_PER_PROB;
    int cell = t >> 6, r = t & 63;
    int wi = 0;
    while (cell >= 8 - wi) { cell -= 8 - wi; ++wi; }
    const int wj = wi + cell;
    const int bi = wi * 64 + r;
    const int j = wj * 64 + lane;

    bool surv = false;
    {
        const float* SA = screen + (size_t)(prob * PRE + bi) * 8; // wave-uniform
        const float* SB = screen + (size_t)(prob * PRE + j) * 8;
        if (j > bi) {
            float4 a4 = *(const float4*)SA;           // x,y,zlo,zhi
            float4 b4 = *(const float4*)SB;
            float hz = fminf(a4.w, b4.w) - fmaxf(a4.z, b4.z);
            if (hz > 0.0f) {
                float ddx = a4.x - b4.x, ddy = a4.y - b4.y;
                float rs = SA[4] + SB[4] + 0.01f;
                surv = (ddx * ddx + ddy * ddy <= rs * rs);
            }
        }
    }
    unsigned long long sm = __ballot(surv);   // wave-uniform survivor set
    unsigned long long supw = 0ull;
    const double* A = boxdata + (size_t)(prob * PRE + bi) * 20;

    while (sm) {
        int jb = __ffsll(sm) - 1;
        sm &= sm - 1ull;
        const int bj = wj * 64 + jb;
        const double* B = boxdata + (size_t)(prob * PRE + bj) * 20;

        // ---- exact, wave-uniform early-outs (skip the polygon body) ----
        double hzd = fmin(A[7], B[7]) - fmax(A[6], B[6]);
        if (hzd <= 0.0) continue;                    // no z overlap -> !sup
        {
            double ddx = B[0] - A[0], ddy = B[1] - A[1];
            double ca = A[2], sa = A[3], cb2 = B[2], sb2 = B[3];
            double cd = fabs(ca * cb2 + sa * sb2);   // |cos dtheta|
            double sd = fabs(sa * cb2 - ca * sb2);   // |sin dtheta|
            double pax = fabs(ddx * ca + ddy * sa);
            double pay = fabs(-ddx * sa + ddy * ca);
            double pbx = fabs(ddx * cb2 + ddy * sb2);
            double pby = fabs(-ddx * sb2 + ddy * cb2);
            // SAT: strictly separated => inter == 0 => !sup (exact)
            if (pax > A[4] + B[4] * cd + B[5] * sd) continue;
            if (pay > A[5] + B[4] * sd + B[5] * cd) continue;
            if (pbx > B[4] + A[4] * cd + A[5] * sd) continue;
            if (pby > B[5] + A[4] * sd + A[5] * cd) continue;
            // IoU upper bound: inter <= min(areaA, areaB); f increasing in i3
            double areaA = 4.0 * A[4] * A[5], areaB = 4.0 * B[4] * B[5];
            double i3m = fmin(areaA, areaB) * hzd;
            double den = A[8] + B[8] - i3m;
            if (den < 1e-8) den = 1e-8;
            if (!(i3m / den > (double)NMS_TH)) continue;
        }

        // lane owns one candidate point: 0-3 A-corners, 4-7 B-corners,
        // 8-23 edge intersections (reference construction order)
        double PX = 0.0, PY = 0.0;
        bool valid = false;
        if (lane < 8) {
            const double* S = (lane < 4) ? A : B;
            const double* O = (lane < 4) ? B : A;
            int m = lane & 3;
            PX = S[10 + m]; PY = S[14 + m];
            double rx = PX - O[0], ry = PY - O[1];
            double u =  rx * O[2] + ry * O[3];
            double v = -rx * O[3] + ry * O[2];
            valid = (fabs(u) <= O[4] + 1e-5) && (fabs(v) <= O[5] + 1e-5);
        } else if (lane < 24) {
            int e = lane - 8, m = e >> 2, nn = e & 3;
            double ax = A[10 + m], ay = A[14 + m];
            double rax = A[10 + ((m + 1) & 3)] - ax;
            double ray = A[14 + ((m + 1) & 3)] - ay;
            double bx = B[10 + nn], by = B[14 + nn];
            double rbx = B[10 + ((nn + 1) & 3)] - bx;
            double rby = B[14 + ((nn + 1) & 3)] - by;
            double d = rax * rby - ray * rbx;
            if (fabs(d) > 1e-8) {
                double qx = bx - ax, qy = by - ay;
                double tt = (qx * rby - qy * rbx) / d;
                double uu = (qx * ray - qy * rax) / d;
                valid = (tt >= 0.0 && tt <= 1.0 && uu >= 0.0 && uu <= 1.0);
                PX = ax + tt * rax; PY = ay + tt * ray;
            }
        }
        if (!valid) { PX = 0.0; PY = 0.0; }

        unsigned long long bal = __ballot(valid);  // valid only in lanes 0-23
        int cnt = __popcll(bal);
        double sx = PX, sy = PY;          // invalid lanes contribute 0
        #pragma unroll
        for (int off = 16; off; off >>= 1) {       // 32-group butterfly
            sx += __shfl_xor(sx, off);
            sy += __shfl_xor(sy, off);
        }
        int cdiv = cnt > 0 ? cnt : 1;     // ref: / max(cnt, 1)
        double cxc = sx / cdiv, cyc = sy / cdiv;

        double ang = valid ? atan2(PY - cyc, PX - cxc) : 1e9;
        int sidx = lane;                  // construction order == ref slots

        // 32-lane bitonic sort asc by (ang, sidx) == numpy stable argsort
        #pragma unroll
        for (int k = 2; k <= 32; k <<= 1) {
            #pragma unroll
            for (int jj = k >> 1; jj > 0; jj >>= 1) {
                double oang = __shfl_xor(ang, jj);
                double opx  = __shfl_xor(PX, jj);
                double opy  = __shfl_xor(PY, jj);
                int    oidx = __shfl_xor(sidx, jj);
                bool iLow = (lane & jj) == 0;
                bool dirUp = (lane & k) == 0;
                bool mineFirst = (ang < oang) || (ang == oang && sidx < oidx);
                bool keepMine = (mineFirst == (iLow == dirUp));
                if (!keepMine) { ang = oang; PX = opx; PY = opy; sidx = oidx; }
            }
        }

        // centered shoelace over sorted lanes [0, cnt)  (cnt <= 24 < 32)
        double nxp = __shfl(PX, (lane + 1) & 31);
        double nyp = __shfl(PY, (lane + 1) & 31);
        double fx  = __shfl(PX, 0);
        double fy  = __shfl(PY, 0);
        bool last = (lane == cnt - 1);
        double qx = last ? fx : nxp, qy = last ? fy : nyp;
        double contrib = 0.0;
        if (lane < cnt)
            contrib = (PX - cxc) * (qy - cyc) - (PY - cyc) * (qx - cxc);
        #pragma unroll
        for (int off = 16; off; off >>= 1) contrib += __shfl_xor(contrib, off);
        double inter = (cnt >= 3) ? 0.5 * fabs(contrib) : 0.0;

        if (lane == 0) {
            double zt = fmin(A[7], B[7]);
            double zb = fmax(A[6], B[6]);
            double hz = zt - zb;
            bool sup = false;
            if (hz > 0.0) {
                double i3 = inter * hz;
                double den = A[8] + B[8] - i3;
                if (den < 1e-8) den = 1e-8;
                sup = (i3 / den) > (double)NMS_TH;
            }
            if (sup) supw |= 1ull << jb;
        }
    }

    if (lane == 0)
        mask[(size_t)(prob * PRE + bi) * 8 + wj] = supw;   // exclusive word
}

// 6 blocks x 256: keep-iterating greedy NMS (<=100 iterations; i = min
// remaining row => rows < i already removed => lower-triangle garbage mask
// bits provably harmless) + padded output.
__global__ __launch_bounds__(256) void nms_out_kernel(
    const float* __restrict__ boxes, const uint32_t* __restrict__ cand_idx,
    const float* __restrict__ cand_score,
    const unsigned long long* __restrict__ mask, float* __restrict__ out)
{
    const int p = blockIdx.x;
    const int b = p / NCLS, k = p % NCLS;
    const int tid = threadIdx.x;

    __shared__ unsigned long long smask[PRE * 8];   // 32 KB
    __shared__ float sscore[PRE];
    __shared__ int slist[POST];
    __shared__ int scnt;

    for (int w = tid; w < PRE * 8; w += 256)
        smask[w] = mask[(size_t)p * PRE * 8 + w];
    for (int i = tid; i < PRE; i += 256)
        sscore[i] = cand_score[p * PRE + i];
    __syncthreads();

    if (tid < 64) {
        const int ln = tid;
        unsigned long long rem = 0ull;
        #pragma unroll
        for (int w = 0; w < 8; ++w) {
            unsigned long long bw = __ballot(sscore[w * 64 + ln] >= SCORE_TH);
            if (ln == w) rem = bw;
        }
        int c = 0;
        for (;;) {
            int cv = rem ? ((ln << 6) + (__ffsll(rem) - 1)) : 4096;
            int o1 = __shfl_xor(cv, 1); cv = cv < o1 ? cv : o1;
            int o2 = __shfl_xor(cv, 2); cv = cv < o2 ? cv : o2;
            int o4 = __shfl_xor(cv, 4); cv = cv < o4 ? cv : o4;
            int i = __shfl(cv, 0);
            if (i >= 4096) break;
            if (ln == 0) slist[c] = i;
            ++c;
            if (c >= POST) break;
            unsigned long long mm = (ln < 8) ? smask[i * 8 + ln] : 0ull;
            if (ln == (i >> 6)) mm |= 1ull << (i & 63);
            rem &= ~mm;
        }
        if (ln == 0) scnt = c;
    }
    __syncthreads();

    const int cnt2 = scnt;
    for (int t2 = tid; t2 < POST; t2 += 256) {
        int row = b * (NCLS * POST) + k * POST + t2;          // 0..599
        float* ob = out + (size_t)row * 7;
        float* os = out + (size_t)NB * NCLS * POST * 7 + row;
        float* ol = out + (size_t)NB * NCLS * POST * 7 + (size_t)NB * NCLS * POST + row;
        if (t2 < cnt2) {
            int rr = slist[t2];
            uint32_t idx = cand_idx[p * PRE + rr];
            const float* bp = boxes + ((size_t)b * NPTS + idx) * 7;
            #pragma unroll
            for (int c7 = 0; c7 < 7; ++c7) ob[c7] = bp[c7];
            *os = sscore[rr];
            *ol = (float)(k + 1);
        } else {
            #pragma unroll
            for (int c7 = 0; c7 < 7; ++c7) ob[c7] = 0.0f;
            *os = 0.0f;
            *ol = 0.0f;
        }
    }
}

extern "C" void kernel_launch(void* const* d_in, const int* in_sizes, int n_in,
                              void* d_out, int out_size, void* d_ws, size_t ws_size,
                              hipStream_t stream)
{
    (void)in_sizes; (void)n_in; (void)out_size; (void)ws_size;
    const float* cls   = (const float*)d_in[0];   // (2,100000,3) f32
    const float* boxes = (const float*)d_in[1];   // (2,100000,7) f32
    float* out = (float*)d_out;

    char* ws = (char*)d_ws;
    uint32_t* hist_part   = (uint32_t*)(ws);
    uint32_t* ctrs        = (uint32_t*)(ws + 230400);
    unsigned long long* cand = (unsigned long long*)(ws + 230528);
    unsigned long long* mask = (unsigned long long*)(ws + 279680);
    uint32_t* cand_idx    = (uint32_t*)(ws + 476288);
    float*    cand_score  = (float*)   (ws + 488576);
    double*   boxdata     = (double*)  (ws + 500864);
    float*    screen      = (float*)   (ws + 992384);

    // 5 dispatches, all R2-verified components; kernel boundaries are the
    // only cross-block ordering (no fences, no gates, no grid.sync).
    hipLaunchKernelGGL(hist_kernel, dim3(NB * NKB), dim3(1024), 0, stream,
                       cls, hist_part, ctrs);
    hipLaunchKernelGGL(compact_kernel, dim3(NPROB * NCHUNK), dim3(1024),
                       0, stream, cls, hist_part, ctrs, cand);
    hipLaunchKernelGGL(sort_geom_kernel, dim3(NPROB), dim3(1024), 0, stream,
                       boxes, cand, ctrs, cand_idx, cand_score, boxdata, screen);
    hipLaunchKernelGGL(iou_kernel, dim3(NPROB * WAVES_PER_PROB / 4),
                       dim3(256), 0, stream, screen, boxdata, mask);
    hipLaunchKernelGGL(nms_out_kernel, dim3(NPROB), dim3(256), 0, stream,
                       boxes, cand_idx, cand_score, mask, out);
}